// Round 1
// baseline (629.282 us; speedup 1.0000x reference)
//
#include <hip/hip_runtime.h>

// Space-to-depth k=2 on (32,224,224,64) fp32 NHWC -> (32,112,112,256),
// output channel order (kh, kw, C).
//
// out[b][ho][wo][(kh*2+kw)*64 + c] = in[b][2*ho+kh][2*wo+kw][c]
//
// One float4 (16B) per thread, indexed by OUTPUT position so writes are
// perfectly contiguous. Reads: within a 64-lane wave, lanes 0..31 cover
// kh=0 (input row 2ho, w=2wo..2wo+1, contiguous 512B) and lanes 32..63
// cover kh=1 (row 2ho+1, contiguous 512B). Two 512B coalesced reads +
// one 1KB coalesced write per wave.

__global__ __launch_bounds__(256) void s2d_kernel(
    const float4* __restrict__ in, float4* __restrict__ out) {
    int idx = blockIdx.x * blockDim.x + threadIdx.x;  // float4 index in output

    int c4  = idx & 63;   // which float4 within the 256-float output vector
    int pos = idx >> 6;   // linear (b, ho, wo)
    int wo  = pos % 112;
    int t   = pos / 112;
    int ho  = t % 112;
    int b   = t / 112;

    int kh = c4 >> 5;         // c4 in [0,32) -> kh=0, [32,64) -> kh=1
    int kw = (c4 >> 4) & 1;   // within kh: first 16 float4s kw=0, next 16 kw=1
    int cc = c4 & 15;         // float4 index within the 64-channel segment

    int h = 2 * ho + kh;
    int w = 2 * wo + kw;
    // input flat float4 index: ((b*224 + h)*224 + w)*16 + cc   (64 ch = 16 float4)
    int src = (((b * 224) + h) * 224 + w) * 16 + cc;

    out[idx] = in[src];
}

extern "C" void kernel_launch(void* const* d_in, const int* in_sizes, int n_in,
                              void* d_out, int out_size, void* d_ws, size_t ws_size,
                              hipStream_t stream) {
    const float4* in  = (const float4*)d_in[0];
    float4*       out = (float4*)d_out;

    // total elements = 32*224*224*64 = 102,760,448 ; /4 = 25,690,112 float4
    const int total4 = 32 * 224 * 224 * 64 / 4;
    const int threads = 256;
    const int blocks = total4 / threads;  // divides exactly: 100,352

    s2d_kernel<<<blocks, threads, 0, stream>>>(in, out);
}